// Round 15
// baseline (13.686 us; speedup 1.0000x reference)
//
#include <hip/hip_runtime.h>
#include <math.h>

#define D 512
#define NREL 512
#define NB 1024

typedef _Float16 f16x8 __attribute__((ext_vector_type(8)));
typedef float f32x4 __attribute__((ext_vector_type(4)));

// tanh(x)/x and atanh(x)/x as even polynomials in u = x^2 (x = 0.1*||row|| <= ~0.05,
// u <= 0.0025; truncation error < 1e-8, fp32-exact).
__device__ __forceinline__ float tanhc(float u) {
    return 1.0f + u * (-0.33333333f + u * (0.13333333f - u * 0.05396825f));
}
__device__ __forceinline__ float atanhc(float u) {
    return 1.0f + u * (0.33333333f + u * (0.2f + u * 0.14285714f));
}

template <int N>
__device__ __forceinline__ void wave_sum_n(float* v) {
#pragma unroll
    for (int m = 1; m < 64; m <<= 1) {
#pragma unroll
        for (int i = 0; i < N; ++i) v[i] += __shfl_xor(v[i], m, 64);
    }
}

// Single dispatch, 256 blocks (1/CU), 1024 threads (16 waves/CU).
// Block = 32m x 64n tile. Phase A stages RAW fp16 (rel_raw, R(s), o) into
// swizzled LDS immediately after load (no reduction dependency); reductions
// feed only small per-row scalar arrays. Phase B: two MFMA GEMMs
// (P1 = R(s)*rel_raw^T, P2 = o*rel_raw^T); epilogue combines
// qd = es_n * (qa_m*P1 + qb_m*P2).
__global__ __launch_bounds__(1024, 1) void fused_kernel(
        const float* __restrict__ ent, const float* __restrict__ rel,
        const int* __restrict__ trip, const float* __restrict__ grot,
        const float* __restrict__ bias, float* __restrict__ out) {
    extern __shared__ char smem[];
    _Float16* RELs = (_Float16*)smem;            // 64 x 512 fp16 raw (swz)
    _Float16* RTs  = RELs + 64 * 512;            // 32 x 512 fp16 R(s) (swz)
    _Float16* OVs  = RTs + 32 * 512;             // 32 x 512 fp16 o    (swz)
    f32x4* lacc    = (f32x4*)(OVs + 32 * 512);   // [2 P][2 wm][4 wn][64]
    float* x2s = (float*)(lacc + 2 * 2 * 4 * 64);// 32
    float* qas = x2s + 32;                       // 32
    float* qbs = qas + 32;                       // 32
    float* esn = qbs + 32;                       // 64
    float* y2n = esn + 64;                       // 64

    const int t = threadIdx.x, wid = t >> 6, lane = t & 63;
    // XCD swizzle (R14-proven): xcd = bid%8 owns a 4n x 8m region
    const int bid = blockIdx.x;
    const int xcd = bid & 7, slot = bid >> 3;
    const int nx  = (xcd & 1) * 4 + (slot & 3);
    const int my  = (xcd >> 1) * 8 + (slot >> 2);
    const int n0 = nx * 64, m0 = my * 32;
    const float c = 0.01f;

    // ---- trip indices first (they gate the ent gather) ----
    const int lq0 = wid * 2, lq1 = wid * 2 + 1;  // local q rows
    const int si0 = trip[3 * (m0 + lq0)], oi0 = trip[3 * (m0 + lq0) + 2];
    const int si1 = trip[3 * (m0 + lq1)], oi1 = trip[3 * (m0 + lq1) + 2];

    // ---- rel: 4 rows/wave -> raw fp16 to LDS immediately; uu partials ----
    float v[10];
    float4 ra[4][2];
#pragma unroll
    for (int j = 0; j < 4; ++j) {
        const int r = n0 + wid * 4 + j;
        ra[j][0] = *(const float4*)(rel + (size_t)r * D + lane * 8);
        ra[j][1] = *(const float4*)(rel + (size_t)r * D + lane * 8 + 4);
    }
#pragma unroll
    for (int j = 0; j < 4; ++j) {
        const float4 a0 = ra[j][0], a1 = ra[j][1];
        v[6 + j] = a0.x*a0.x + a0.y*a0.y + a0.z*a0.z + a0.w*a0.w
                 + a1.x*a1.x + a1.y*a1.y + a1.z*a1.z + a1.w*a1.w;
        f16x8 h;
        h[0]=(_Float16)a0.x; h[1]=(_Float16)a0.y; h[2]=(_Float16)a0.z; h[3]=(_Float16)a0.w;
        h[4]=(_Float16)a1.x; h[5]=(_Float16)a1.y; h[6]=(_Float16)a1.z; h[7]=(_Float16)a1.w;
        const int lr = wid * 4 + j;
        *(f16x8*)(RELs + lr * 512 + ((lane * 8) ^ ((lr & 7) << 3))) = h;
    }

    // ---- q: 2 rows/wave -> rotate, stage R(s) and o raw; partials ----
    const float4 ang = *(const float4*)(grot + 4 * lane);
    const float ca0 = __cosf(ang.x), sa0 = __sinf(ang.x);
    const float ca1 = __cosf(ang.y), sa1 = __sinf(ang.y);
    const float ca2 = __cosf(ang.z), sa2 = __sinf(ang.z);
    const float ca3 = __cosf(ang.w), sa3 = __sinf(ang.w);
#pragma unroll
    for (int i = 0; i < 2; ++i) {
        const int si = i ? si1 : si0, oi = i ? oi1 : oi0;
        const float4 s0 = *(const float4*)(ent + (size_t)si * D + lane * 8);
        const float4 s1 = *(const float4*)(ent + (size_t)si * D + lane * 8 + 4);
        const float4 o0 = *(const float4*)(ent + (size_t)oi * D + lane * 8);
        const float4 o1 = *(const float4*)(ent + (size_t)oi * D + lane * 8 + 4);
        float rt[8];
        rt[0] = ca0 * s0.x - sa0 * s0.y; rt[1] = sa0 * s0.x + ca0 * s0.y;
        rt[2] = ca1 * s0.z - sa1 * s0.w; rt[3] = sa1 * s0.z + ca1 * s0.w;
        rt[4] = ca2 * s1.x - sa2 * s1.y; rt[5] = sa2 * s1.x + ca2 * s1.y;
        rt[6] = ca3 * s1.z - sa3 * s1.w; rt[7] = sa3 * s1.z + ca3 * s1.w;
        const int lq = wid * 2 + i;
        const int sw = (lane * 8) ^ ((lq & 7) << 3);
        f16x8 hr, ho;
        hr[0]=(_Float16)rt[0]; hr[1]=(_Float16)rt[1]; hr[2]=(_Float16)rt[2]; hr[3]=(_Float16)rt[3];
        hr[4]=(_Float16)rt[4]; hr[5]=(_Float16)rt[5]; hr[6]=(_Float16)rt[6]; hr[7]=(_Float16)rt[7];
        ho[0]=(_Float16)o0.x; ho[1]=(_Float16)o0.y; ho[2]=(_Float16)o0.z; ho[3]=(_Float16)o0.w;
        ho[4]=(_Float16)o1.x; ho[5]=(_Float16)o1.y; ho[6]=(_Float16)o1.z; ho[7]=(_Float16)o1.w;
        *(f16x8*)(RTs + lq * 512 + sw) = hr;
        *(f16x8*)(OVs + lq * 512 + sw) = ho;
        // partials: ss (= ||rt||^2), oo, rw (= rt.o)
        v[3 * i + 0] = rt[0]*rt[0] + rt[1]*rt[1] + rt[2]*rt[2] + rt[3]*rt[3]
                     + rt[4]*rt[4] + rt[5]*rt[5] + rt[6]*rt[6] + rt[7]*rt[7];
        v[3 * i + 1] = o0.x*o0.x + o0.y*o0.y + o0.z*o0.z + o0.w*o0.w
                     + o1.x*o1.x + o1.y*o1.y + o1.z*o1.z + o1.w*o1.w;
        v[3 * i + 2] = rt[0]*o0.x + rt[1]*o0.y + rt[2]*o0.z + rt[3]*o0.w
                     + rt[4]*o1.x + rt[5]*o1.y + rt[6]*o1.z + rt[7]*o1.w;
    }
    wave_sum_n<10>(v);

    if (lane == 0) {
#pragma unroll
        for (int i = 0; i < 2; ++i) {
            const float ss = v[3 * i], oo = v[3 * i + 1], rw = v[3 * i + 2];
            const float ls  = atanhc(c * ss);
            const float nu2 = ls * ls * ss;
            const float eq  = tanhc(c * nu2);
            const float rr  = eq * eq * nu2;
            const float ro  = eq * ls * rw;
            const float A1  = 1.0f - 2.0f * c * ro + c * oo;
            const float B1  = 1.0f - c * rr;
            const float den = fmaxf(1.0f - 2.0f * c * ro + c * c * rr * oo, 1e-15f);
            const float inv = 1.0f / den;
            const int lq = wid * 2 + i;
            qas[lq] = -A1 * eq * ls * inv;       // multiplies P1 = R(s).rel
            qbs[lq] = B1 * inv;                  // multiplies P2 = o.rel
            x2s[lq] = (A1 * A1 * rr - 2.0f * A1 * B1 * ro + B1 * B1 * oo) * inv * inv;
        }
#pragma unroll
        for (int j = 0; j < 4; ++j) {
            const float uu = v[6 + j];
            const float er = tanhc(c * uu);
            const int lr = wid * 4 + j;
            esn[lr] = er;
            y2n[lr] = er * er * uu;
        }
    }
    __syncthreads();

    // ================= phase B: two GEMMs =================
    const int wm = wid & 1, wn = (wid >> 1) & 3, kh = wid >> 3;
    const int rA = wm * 16 + (lane & 15);
    const int rB = wn * 16 + (lane & 15);
    const int kg = lane >> 4;
    const _Float16* pa1 = RTs + rA * 512;
    const _Float16* pa2 = OVs + rA * 512;
    const _Float16* pb  = RELs + rB * 512;
    const int xa = (rA & 7) << 3, xb = (rB & 7) << 3;

    f32x4 acc1 = {}, acc2 = {};
#pragma unroll
    for (int ks = kh * 8; ks < kh * 8 + 8; ++ks) {
        const int ko = ks * 32 + kg * 8;
        const f16x8 b  = *(const f16x8*)(pb + (ko ^ xb));
        const f16x8 a1 = *(const f16x8*)(pa1 + (ko ^ xa));
        const f16x8 a2 = *(const f16x8*)(pa2 + (ko ^ xa));
        acc1 = __builtin_amdgcn_mfma_f32_16x16x32_f16(a1, b, acc1, 0, 0, 0);
        acc2 = __builtin_amdgcn_mfma_f32_16x16x32_f16(a2, b, acc2, 0, 0, 0);
    }

    if (kh == 1) {
        lacc[((0 * 2 + wm) * 4 + wn) * 64 + lane] = acc1;
        lacc[((1 * 2 + wm) * 4 + wn) * 64 + lane] = acc2;
    }
    __syncthreads();
    if (kh == 0) {
        acc1 += lacc[((0 * 2 + wm) * 4 + wn) * 64 + lane];
        acc2 += lacc[((1 * 2 + wm) * 4 + wn) * 64 + lane];

        // C/D layout: col = lane&15, row = (lane>>4)*4 + reg
        const int crow = (lane >> 4) * 4, ccol = lane & 15;
        const int nl = wn * 16 + ccol;
        const int n  = n0 + nl;
        const float er = esn[nl];
        const float Y2 = y2n[nl];
        const float bn = bias[n];
#pragma unroll
        for (int r = 0; r < 4; ++r) {
            const int ml = wm * 16 + crow + r;
            const float qd = er * (qas[ml] * acc1[r] + qbs[ml] * acc2[r]);
            const float X2 = x2s[ml];
            const float B1 = 1.0f - c * X2;
            const float A1  = 1.0f - 2.0f * c * qd + c * Y2;
            const float den = fmaxf(1.0f - 2.0f * c * qd + c * c * X2 * Y2, 1e-15f);
            const float num2 = A1 * A1 * X2 - 2.0f * A1 * B1 * qd + B1 * B1 * Y2;
            out[(size_t)(m0 + ml) * NREL + n] = -(num2 / (den * den)) + bn;
        }
    }
}

extern "C" void kernel_launch(void* const* d_in, const int* in_sizes, int n_in,
                              void* d_out, int out_size, void* d_ws, size_t ws_size,
                              hipStream_t stream) {
    const float* ent  = (const float*)d_in[0];   // (20000, 512)
    const float* rel  = (const float*)d_in[1];   // (512, 512)
    const int*   trip = (const int*)d_in[2];     // (1024, 3)
    const float* grot = (const float*)d_in[3];   // (256,)
    const float* bias = (const float*)d_in[4];   // (512,)
    float* out = (float*)d_out;                  // (1024, 512)

    const size_t shmem = (size_t)(64 * 512 + 32 * 512 + 32 * 512) * sizeof(_Float16)
                       + (size_t)(2 * 2 * 4 * 64) * sizeof(f32x4)
                       + (size_t)(32 * 3 + 64 * 2) * sizeof(float);   // ~145 KB
    fused_kernel<<<dim3(256), dim3(1024), shmem, stream>>>(
        ent, rel, trip, grot, bias, out);
}

// Round 16
// 11.853 us; speedup vs baseline: 1.1547x; 1.1547x over previous
//
#include <hip/hip_runtime.h>
#include <math.h>

#define D 512
#define NREL 512
#define NB 1024

typedef _Float16 f16x8 __attribute__((ext_vector_type(8)));
typedef float f32x4 __attribute__((ext_vector_type(4)));

// tanh(x)/x and atanh(x)/x as even polynomials in u = x^2 (x <= ~0.05 here;
// truncation error < 1e-8, fp32-exact).
__device__ __forceinline__ float tanhc(float u) {
    return 1.0f + u * (-0.33333333f + u * (0.13333333f - u * 0.05396825f));
}
__device__ __forceinline__ float atanhc(float u) {
    return 1.0f + u * (0.33333333f + u * (0.2f + u * 0.14285714f));
}

// diag of one 16x16 tile of (Arows · Brows^T), K = 512, XOR-swizzled LDS rows.
// C/D layout: col = lane&15, row = (lane>>4)*4 + reg  ->  lane holds diag elem
// (col) iff (col>>2) == (lane>>4); that elem is acc[col&3].
__device__ __forceinline__ void diag_gemm(
        const _Float16* __restrict__ Abase, const _Float16* __restrict__ Bbase,
        int rowA, int rowB, float* __restrict__ dst, int lane) {
    const int r15 = lane & 15, kg = lane >> 4;
    const _Float16* pa = Abase + (size_t)(rowA + r15) * 512;
    const _Float16* pb = Bbase + (size_t)(rowB + r15) * 512;
    const int xa = ((rowA + r15) & 7) << 3;
    const int xb = ((rowB + r15) & 7) << 3;
    f32x4 acc = {};
#pragma unroll
    for (int ks = 0; ks < 16; ++ks) {
        const int ko = ks * 32 + kg * 8;
        const f16x8 a = *(const f16x8*)(pa + (ko ^ xa));
        const f16x8 b = *(const f16x8*)(pb + (ko ^ xb));
        acc = __builtin_amdgcn_mfma_f32_16x16x32_f16(a, b, acc, 0, 0, 0);
    }
    if ((r15 >> 2) == kg) dst[r15] = acc[r15 & 3];
}

// Single dispatch, 256 blocks (1/CU), 512 threads. Block = 32m x 64n tile.
// Phase A: stage RAW fp16 (rel, R(s), o) -> swizzled LDS, no reductions.
// Phase B1: row norms/dots via MFMA self-GEMM diagonals (no shuffles).
// Phase B2: 96-wide scalar chains. Phase B3: dual GEMM + fused epilogue.
__global__ __launch_bounds__(512, 1) void fused_kernel(
        const float* __restrict__ ent, const float* __restrict__ rel,
        const int* __restrict__ trip, const float* __restrict__ grot,
        const float* __restrict__ bias, float* __restrict__ out) {
    extern __shared__ char smem[];
    _Float16* RELs = (_Float16*)smem;            // 64 x 512 fp16 raw (swz)
    _Float16* RTs  = RELs + 64 * 512;            // 32 x 512 fp16 R(s) (swz)
    _Float16* OVs  = RTs + 32 * 512;             // 32 x 512 fp16 o    (swz)
    float* ssA = (float*)(OVs + 32 * 512);       // 32
    float* ooA = ssA + 32;                       // 32
    float* rwA = ooA + 32;                       // 32
    float* uuA = rwA + 32;                       // 64
    float* qas = uuA + 64;                       // 32
    float* qbs = qas + 32;                       // 32
    float* x2s = qbs + 32;                       // 32
    float* esn = x2s + 32;                       // 64
    float* y2n = esn + 64;                       // 64

    const int t = threadIdx.x, wid = t >> 6, lane = t & 63;
    // XCD swizzle (R14-proven): xcd = bid%8 owns a 4n x 8m region
    const int bid = blockIdx.x;
    const int xcd = bid & 7, slot = bid >> 3;
    const int nx  = (xcd & 1) * 4 + (slot & 3);
    const int my  = (xcd >> 1) * 8 + (slot >> 2);
    const int n0 = nx * 64, m0 = my * 32;
    const float c = 0.01f;

    // ---- trip indices first (they gate the ent gather) ----
    int si[4], oi[4];
#pragma unroll
    for (int i = 0; i < 4; ++i) {
        const int b = m0 + wid * 4 + i;
        si[i] = trip[3 * b];
        oi[i] = trip[3 * b + 2];
    }

    // ---- rel: 8 rows/wave -> raw fp16 to LDS immediately ----
#pragma unroll
    for (int j = 0; j < 8; ++j) {
        const int lr = wid * 8 + j;
        const float4 a0 = *(const float4*)(rel + (size_t)(n0 + lr) * D + lane * 8);
        const float4 a1 = *(const float4*)(rel + (size_t)(n0 + lr) * D + lane * 8 + 4);
        f16x8 h;
        h[0]=(_Float16)a0.x; h[1]=(_Float16)a0.y; h[2]=(_Float16)a0.z; h[3]=(_Float16)a0.w;
        h[4]=(_Float16)a1.x; h[5]=(_Float16)a1.y; h[6]=(_Float16)a1.z; h[7]=(_Float16)a1.w;
        *(f16x8*)(RELs + lr * 512 + ((lane * 8) ^ ((lr & 7) << 3))) = h;
    }

    // ---- q: 4 rows/wave -> rotate raw s; stage R(s), o ----
    const float4 ang = *(const float4*)(grot + 4 * lane);
    const float ca0 = __cosf(ang.x), sa0 = __sinf(ang.x);
    const float ca1 = __cosf(ang.y), sa1 = __sinf(ang.y);
    const float ca2 = __cosf(ang.z), sa2 = __sinf(ang.z);
    const float ca3 = __cosf(ang.w), sa3 = __sinf(ang.w);
#pragma unroll
    for (int i = 0; i < 4; ++i) {
        const float4 s0 = *(const float4*)(ent + (size_t)si[i] * D + lane * 8);
        const float4 s1 = *(const float4*)(ent + (size_t)si[i] * D + lane * 8 + 4);
        const float4 o0 = *(const float4*)(ent + (size_t)oi[i] * D + lane * 8);
        const float4 o1 = *(const float4*)(ent + (size_t)oi[i] * D + lane * 8 + 4);
        f16x8 hr, ho;
        hr[0] = (_Float16)(ca0 * s0.x - sa0 * s0.y);
        hr[1] = (_Float16)(sa0 * s0.x + ca0 * s0.y);
        hr[2] = (_Float16)(ca1 * s0.z - sa1 * s0.w);
        hr[3] = (_Float16)(sa1 * s0.z + ca1 * s0.w);
        hr[4] = (_Float16)(ca2 * s1.x - sa2 * s1.y);
        hr[5] = (_Float16)(sa2 * s1.x + ca2 * s1.y);
        hr[6] = (_Float16)(ca3 * s1.z - sa3 * s1.w);
        hr[7] = (_Float16)(sa3 * s1.z + ca3 * s1.w);
        ho[0]=(_Float16)o0.x; ho[1]=(_Float16)o0.y; ho[2]=(_Float16)o0.z; ho[3]=(_Float16)o0.w;
        ho[4]=(_Float16)o1.x; ho[5]=(_Float16)o1.y; ho[6]=(_Float16)o1.z; ho[7]=(_Float16)o1.w;
        const int lq = wid * 4 + i;
        const int sw = (lane * 8) ^ ((lq & 7) << 3);
        *(f16x8*)(RTs + lq * 512 + sw) = hr;
        *(f16x8*)(OVs + lq * 512 + sw) = ho;
    }
    __syncthreads();

    // ---- phase B1: norms/dots via MFMA diag tiles (10 tasks over 8 waves) --
    switch (wid) {
        case 0: diag_gemm(RTs,  RTs,   0,  0, ssA,      lane);
                diag_gemm(RELs, RELs, 32, 32, uuA + 32, lane); break;
        case 1: diag_gemm(RTs,  RTs,  16, 16, ssA + 16, lane);
                diag_gemm(RELs, RELs, 48, 48, uuA + 48, lane); break;
        case 2: diag_gemm(OVs,  OVs,   0,  0, ooA,      lane); break;
        case 3: diag_gemm(OVs,  OVs,  16, 16, ooA + 16, lane); break;
        case 4: diag_gemm(RTs,  OVs,   0,  0, rwA,      lane); break;
        case 5: diag_gemm(RTs,  OVs,  16, 16, rwA + 16, lane); break;
        case 6: diag_gemm(RELs, RELs,  0,  0, uuA,      lane); break;
        case 7: diag_gemm(RELs, RELs, 16, 16, uuA + 16, lane); break;
    }
    __syncthreads();

    // ---- phase B2: scalar chains, 96-wide ----
    if (wid == 0 && lane < 32) {
        const float ss = ssA[lane], oo = ooA[lane], rw = rwA[lane];
        const float ls  = atanhc(c * ss);
        const float nu2 = ls * ls * ss;
        const float eq  = tanhc(c * nu2);
        const float rr  = eq * eq * nu2;
        const float ro  = eq * ls * rw;
        const float A1  = 1.0f - 2.0f * c * ro + c * oo;
        const float B1  = 1.0f - c * rr;
        const float den = fmaxf(1.0f - 2.0f * c * ro + c * c * rr * oo, 1e-15f);
        const float inv = 1.0f / den;
        qas[lane] = -A1 * eq * ls * inv;         // multiplies P1 = R(s).rel
        qbs[lane] = B1 * inv;                    // multiplies P2 = o.rel
        x2s[lane] = (A1 * A1 * rr - 2.0f * A1 * B1 * ro + B1 * B1 * oo) * inv * inv;
    } else if (wid == 1) {
        const float uu = uuA[lane];
        const float er = tanhc(c * uu);
        esn[lane] = er;
        y2n[lane] = er * er * uu;
    }
    __syncthreads();

    // ---- phase B3: dual GEMM (full K per wave) + fused epilogue ----
    const int wm = wid & 1, wn = wid >> 1;       // 2m x 4n wave grid
    const int r15 = lane & 15, kg = lane >> 4;
    const int rA = wm * 16 + r15;
    const int rB = wn * 16 + r15;
    const _Float16* pa1 = RTs + rA * 512;
    const _Float16* pa2 = OVs + rA * 512;
    const _Float16* pb  = RELs + rB * 512;
    const int xa = (rA & 7) << 3, xb = (rB & 7) << 3;

    f32x4 acc1 = {}, acc2 = {};
#pragma unroll
    for (int ks = 0; ks < 16; ++ks) {
        const int ko = ks * 32 + kg * 8;
        const f16x8 b  = *(const f16x8*)(pb + (ko ^ xb));
        const f16x8 a1 = *(const f16x8*)(pa1 + (ko ^ xa));
        const f16x8 a2 = *(const f16x8*)(pa2 + (ko ^ xa));
        acc1 = __builtin_amdgcn_mfma_f32_16x16x32_f16(a1, b, acc1, 0, 0, 0);
        acc2 = __builtin_amdgcn_mfma_f32_16x16x32_f16(a2, b, acc2, 0, 0, 0);
    }

    // epilogue: C/D layout col = lane&15, row = (lane>>4)*4 + reg
    const int crow = kg * 4, ccol = r15;
    const int nl = wn * 16 + ccol;
    const int n  = n0 + nl;
    const float er = esn[nl];
    const float Y2 = y2n[nl];
    const float bn = bias[n];
#pragma unroll
    for (int r = 0; r < 4; ++r) {
        const int ml = wm * 16 + crow + r;
        const float qd = er * (qas[ml] * acc1[r] + qbs[ml] * acc2[r]);
        const float X2 = x2s[ml];
        const float B1 = 1.0f - c * X2;
        const float A1  = 1.0f - 2.0f * c * qd + c * Y2;
        const float den = fmaxf(1.0f - 2.0f * c * qd + c * c * X2 * Y2, 1e-15f);
        const float num2 = A1 * A1 * X2 - 2.0f * A1 * B1 * qd + B1 * B1 * Y2;
        out[(size_t)(m0 + ml) * NREL + n] = -(num2 / (den * den)) + bn;
    }
}

extern "C" void kernel_launch(void* const* d_in, const int* in_sizes, int n_in,
                              void* d_out, int out_size, void* d_ws, size_t ws_size,
                              hipStream_t stream) {
    const float* ent  = (const float*)d_in[0];   // (20000, 512)
    const float* rel  = (const float*)d_in[1];   // (512, 512)
    const int*   trip = (const int*)d_in[2];     // (1024, 3)
    const float* grot = (const float*)d_in[3];   // (256,)
    const float* bias = (const float*)d_in[4];   // (512,)
    float* out = (float*)d_out;                  // (1024, 512)

    const size_t shmem = (size_t)(64 * 512 + 32 * 512 + 32 * 512) * sizeof(_Float16)
                       + (size_t)(32 * 6 + 64 * 3) * sizeof(float);   // ~129.5 KB
    fused_kernel<<<dim3(256), dim3(512), shmem, stream>>>(
        ent, rel, trip, grot, bias, out);
}